// Round 3
// baseline (13437.462 us; speedup 1.0000x reference)
//
#include <hip/hip_runtime.h>
#include <hip/hip_bf16.h>
#include <math.h>

#define BB 64
#define TT 128
#define VV 10000
#define EE 300
#define HH 1024
#define TM1 127

typedef __hip_bfloat16 bf16;
typedef __attribute__((ext_vector_type(8))) short s8v;   // 8 bf16 = 4 VGPRs (MFMA A/B frag)
typedef __attribute__((ext_vector_type(4))) float f4v;   // 4 fp32 (MFMA C/D frag)

// async global->LDS, 16B per lane; LDS dest is wave-uniform base + lane*16
__device__ __forceinline__ void async_copy16(const void* g, void* s) {
    __builtin_amdgcn_global_load_lds((const __attribute__((address_space(1))) void*)g,
                                     (__attribute__((address_space(3))) void*)s, 16, 0, 0);
}

// ---------------- zero ----------------
__global__ void zero_kernel(float* __restrict__ p, int n) {
    int i = blockIdx.x * blockDim.x + threadIdx.x;
    if (i < n) p[i] = 0.0f;
}

// ---------------- embedding gather -> bf16, padded [128*64][320] ----------------
__global__ void embed_kernel(const int* __restrict__ sent,
                             const float* __restrict__ wordvec,
                             bf16* __restrict__ X) {
    int bi = blockIdx.x;          // t*64+b, t in [0,128)
    int t = bi >> 6;
    int b = bi & 63;
    int w = (t < TM1) ? sent[b * TT + t] : 0;
    const float* src = wordvec + (long)w * EE;
    bf16* dst = X + (long)bi * 320;
    for (int e = threadIdx.x; e < 320; e += 64) {
        float v = (t < TM1 && e < EE) ? src[e] : 0.0f;
        dst[e] = __float2bfloat16(v);
    }
}

// ---------------- transpose+convert: src fp32 [K][N] -> dst bf16 [Nrows][Kpad] ----------------
__global__ void transpose_bf16_kernel(const float* __restrict__ src,
                                      bf16* __restrict__ dst,
                                      int K, int N, int Kpad) {
    __shared__ float tile[32][33];
    int n0 = blockIdx.x * 32, k0 = blockIdx.y * 32;
    int tid = threadIdx.x;
    {
        int tn = tid & 31, tk = tid >> 5;
        #pragma unroll
        for (int i = 0; i < 4; i++) {
            int k = tk + i * 8;
            float v = (k0 + k < K && n0 + tn < N) ? src[(long)(k0 + k) * N + n0 + tn] : 0.0f;
            tile[k][tn] = v;
        }
    }
    __syncthreads();
    {
        int wk = tid & 31, wn = tid >> 5;
        #pragma unroll
        for (int i = 0; i < 4; i++) {
            int n = wn + i * 8;
            dst[(long)(n0 + n) * Kpad + k0 + wk] = __float2bfloat16(tile[wk][n]);
        }
    }
}

// ---------------- persistent fused 2-layer LSTM ----------------
// 256 blocks x 512 threads, 1 block/CU (144KB LDS). Blocks 0..127: layer0 (A-role),
// col-slice j = bid (8 hidden cols, all 4 gates). Blocks 128..255: layer1 (B-role), j = bid-128.
// Weights live in LDS in frag-contiguous layout: chunk(seg,gp,kk,L) at ((segbase+gp*K+kk)*64+L)*16B,
// so every ds_read_b128 is 64-lane contiguous (zero bank conflicts).
// Per block: 8 waves = 2 row-halves (m) x 4 K-quarters (kq); per wave per k-step:
// 1 A-frag global load per row-tile (reused across both gate-pairs) + 2 LDS B-frags + 4 MFMA.
// c-state lives in registers (1 value per thread per row-half). Grid barrier per tick
// (tick-indexed counters; all 256 blocks resident by LDS capacity).
__global__ __launch_bounds__(512) void lstm_persistent(
    const bf16* __restrict__ X,
    const bf16* __restrict__ wt_ih0, const bf16* __restrict__ wt_hh0,
    const bf16* __restrict__ wt_ih1, const bf16* __restrict__ wt_hh1,
    const float* __restrict__ b0, const float* __restrict__ b1,
    bf16* __restrict__ h0b0, bf16* __restrict__ h0b1,
    bf16* __restrict__ h1b0, bf16* __restrict__ h1b1,
    bf16* __restrict__ H1, int* __restrict__ bar)
{
    __shared__ __align__(16) char smem[147968];   // 128KB weights + 16.5KB gbuf
    s8v* wlds = (s8v*)smem;
    float* gb = (float*)(smem + 131072);          // [4 kq][32 rows][33] fp32

    const int bid = blockIdx.x;
    const int roleA = (bid < 128);
    const int j = roleA ? bid : bid - 128;        // 8-col slice: hcols j*8..j*8+7
    const int tid = threadIdx.x;
    const int wave = tid >> 6, m = wave & 1, kq = wave >> 1;
    const int L = tid & 63, quad = L >> 4, l16 = L & 15;

    // ---- prologue: stage weights into LDS (one-shot) ----
    if (roleA) {
        for (int c = tid; c < 1280; c += 512) {   // wt_ih0 slice: 2gp x 10k x 64
            int Lc = c & 63, f = c >> 6;
            int gp = (f >= 10) ? 1 : 0, kk = f - gp * 10;
            int q = Lc >> 4, l = Lc & 15;
            int lrow = gp * 16 + l;
            long grow = (long)(lrow >> 3) * HH + j * 8 + (lrow & 7);
            wlds[c] = ((const s8v*)(wt_ih0 + grow * 320))[kk * 4 + q];
        }
        for (int c = tid; c < 4096; c += 512) {   // wt_hh0 slice: 2gp x 32k x 64
            int Lc = c & 63, kk = (c >> 6) & 31, gp = c >> 11;
            int q = Lc >> 4, l = Lc & 15;
            int lrow = gp * 16 + l;
            long grow = (long)(lrow >> 3) * HH + j * 8 + (lrow & 7);
            wlds[1280 + c] = ((const s8v*)(wt_hh0 + grow * HH))[kk * 4 + q];
        }
    } else {
        for (int c = tid; c < 8192; c += 512) {   // wt_ih1 + wt_hh1 slices
            int Lc = c & 63, kk = (c >> 6) & 31, gp = (c >> 11) & 1, seg = c >> 12;
            int q = Lc >> 4, l = Lc & 15;
            int lrow = gp * 16 + l;
            long grow = (long)(lrow >> 3) * HH + j * 8 + (lrow & 7);
            const bf16* wsrc = seg ? wt_hh1 : wt_ih1;
            wlds[c] = ((const s8v*)(wsrc + grow * HH))[kk * 4 + q];
        }
    }
    __syncthreads();   // all waves read all staged chunks

    // per-thread output ownership (tid<256): (row = mp*32 + rr, col = cc)
    const int cc = tid & 7, rr = (tid >> 3) & 31;
    const int hcol = j * 8 + cc;
    const float* bias = roleA ? b0 : b1;
    float bi = 0.f, bff = 0.f, bgg = 0.f, boo = 0.f;
    if (tid < 256) {
        bi  = bias[hcol];
        bff = bias[HH + hcol];
        bgg = bias[2 * HH + hcol];
        boo = bias[3 * HH + hcol];
    }
    float c_lo = 0.f, c_hi = 0.f;   // c-state registers (row-half 0 / 1)

    for (int t = 0; t <= TM1; ++t) {
        const bool act = roleA ? (t < TM1) : (t >= 1);
        const bf16* h0prev = (t & 1) ? h0b0 : h0b1;   // h0(t-1)
        f4v acc[2][2] = {};                            // [rt][gp]
        if (act) {
            if (roleA) {
                {   // seg0: x(t) @ w_ih0, K=320
                    const s8v* xa = (const s8v*)X + (long)t * 64 * 40;
                    const int r0 = (m * 32 + l16) * 40, r1 = r0 + 640;
                    #pragma unroll
                    for (int kk = kq; kk < 10; kk += 4) {
                        s8v bg0 = wlds[kk * 64 + L];
                        s8v bg1 = wlds[640 + kk * 64 + L];
                        s8v a0 = xa[r0 + kk * 4 + quad];
                        s8v a1 = xa[r1 + kk * 4 + quad];
                        acc[0][0] = __builtin_amdgcn_mfma_f32_16x16x32_bf16(a0, bg0, acc[0][0], 0, 0, 0);
                        acc[0][1] = __builtin_amdgcn_mfma_f32_16x16x32_bf16(a0, bg1, acc[0][1], 0, 0, 0);
                        acc[1][0] = __builtin_amdgcn_mfma_f32_16x16x32_bf16(a1, bg0, acc[1][0], 0, 0, 0);
                        acc[1][1] = __builtin_amdgcn_mfma_f32_16x16x32_bf16(a1, bg1, acc[1][1], 0, 0, 0);
                    }
                }
                {   // seg1: h0(t-1) @ w_hh0, K=1024
                    const s8v* ha = (const s8v*)h0prev;
                    const int r0 = (m * 32 + l16) * 128, r1 = r0 + 2048;
                    #pragma unroll
                    for (int kk = kq; kk < 32; kk += 4) {
                        s8v bg0 = wlds[1280 + kk * 64 + L];
                        s8v bg1 = wlds[1280 + 2048 + kk * 64 + L];
                        s8v a0 = ha[r0 + kk * 4 + quad];
                        s8v a1 = ha[r1 + kk * 4 + quad];
                        acc[0][0] = __builtin_amdgcn_mfma_f32_16x16x32_bf16(a0, bg0, acc[0][0], 0, 0, 0);
                        acc[0][1] = __builtin_amdgcn_mfma_f32_16x16x32_bf16(a0, bg1, acc[0][1], 0, 0, 0);
                        acc[1][0] = __builtin_amdgcn_mfma_f32_16x16x32_bf16(a1, bg0, acc[1][0], 0, 0, 0);
                        acc[1][1] = __builtin_amdgcn_mfma_f32_16x16x32_bf16(a1, bg1, acc[1][1], 0, 0, 0);
                    }
                }
            } else {
                const bf16* h1prev = (t & 1) ? h1b1 : h1b0;   // h1(t-2)
                {   // seg0: h0(t-1) @ w_ih1, K=1024
                    const s8v* ha = (const s8v*)h0prev;
                    const int r0 = (m * 32 + l16) * 128, r1 = r0 + 2048;
                    #pragma unroll
                    for (int kk = kq; kk < 32; kk += 4) {
                        s8v bg0 = wlds[kk * 64 + L];
                        s8v bg1 = wlds[2048 + kk * 64 + L];
                        s8v a0 = ha[r0 + kk * 4 + quad];
                        s8v a1 = ha[r1 + kk * 4 + quad];
                        acc[0][0] = __builtin_amdgcn_mfma_f32_16x16x32_bf16(a0, bg0, acc[0][0], 0, 0, 0);
                        acc[0][1] = __builtin_amdgcn_mfma_f32_16x16x32_bf16(a0, bg1, acc[0][1], 0, 0, 0);
                        acc[1][0] = __builtin_amdgcn_mfma_f32_16x16x32_bf16(a1, bg0, acc[1][0], 0, 0, 0);
                        acc[1][1] = __builtin_amdgcn_mfma_f32_16x16x32_bf16(a1, bg1, acc[1][1], 0, 0, 0);
                    }
                }
                {   // seg1: h1(t-2) @ w_hh1, K=1024
                    const s8v* ha = (const s8v*)h1prev;
                    const int r0 = (m * 32 + l16) * 128, r1 = r0 + 2048;
                    #pragma unroll
                    for (int kk = kq; kk < 32; kk += 4) {
                        s8v bg0 = wlds[4096 + kk * 64 + L];
                        s8v bg1 = wlds[4096 + 2048 + kk * 64 + L];
                        s8v a0 = ha[r0 + kk * 4 + quad];
                        s8v a1 = ha[r1 + kk * 4 + quad];
                        acc[0][0] = __builtin_amdgcn_mfma_f32_16x16x32_bf16(a0, bg0, acc[0][0], 0, 0, 0);
                        acc[0][1] = __builtin_amdgcn_mfma_f32_16x16x32_bf16(a0, bg1, acc[0][1], 0, 0, 0);
                        acc[1][0] = __builtin_amdgcn_mfma_f32_16x16x32_bf16(a1, bg0, acc[1][0], 0, 0, 0);
                        acc[1][1] = __builtin_amdgcn_mfma_f32_16x16x32_bf16(a1, bg1, acc[1][1], 0, 0, 0);
                    }
                }
            }
        }

        // epilogue: kq-reduce via gbuf, LSTM elementwise, two passes over row-halves
        bf16* h0out = (t & 1) ? h0b1 : h0b0;
        bf16* h1out = (t & 1) ? h1b0 : h1b1;
        #pragma unroll
        for (int mp = 0; mp < 2; ++mp) {
            __syncthreads();
            if (act && m == mp) {
                #pragma unroll
                for (int rt = 0; rt < 2; ++rt)
                    #pragma unroll
                    for (int gp = 0; gp < 2; ++gp)
                        #pragma unroll
                        for (int i = 0; i < 4; ++i)
                            gb[(kq * 32 + rt * 16 + quad * 4 + i) * 33 + gp * 16 + l16] = acc[rt][gp][i];
            }
            __syncthreads();
            if (act && tid < 256) {
                float s0 = bi, s1 = bff, s2 = bgg, s3 = boo;
                #pragma unroll
                for (int q = 0; q < 4; ++q) {
                    const float* gr = gb + (q * 32 + rr) * 33;
                    s0 += gr[cc];       // gate i at gcol cc
                    s1 += gr[8 + cc];   // gate f
                    s2 += gr[16 + cc];  // gate g
                    s3 += gr[24 + cc];  // gate o
                }
                float cold = mp ? c_hi : c_lo;
                float si = 1.0f / (1.0f + expf(-s0));
                float sf = 1.0f / (1.0f + expf(-s1));
                float so = 1.0f / (1.0f + expf(-s3));
                float cn = sf * cold + si * tanhf(s2);
                float hn = so * tanhf(cn);
                if (mp) c_hi = cn; else c_lo = cn;
                int row = mp * 32 + rr;
                bf16 hb = __float2bfloat16(hn);
                if (roleA) {
                    h0out[row * HH + hcol] = hb;
                } else {
                    h1out[row * HH + hcol] = hb;
                    H1[((long)row * TM1 + (t - 1)) * HH + hcol] = hb;
                }
            }
        }

        // grid barrier between ticks (cross-XCD release/acquire via threadfence)
        if (t < TM1) {
            __threadfence();
            __syncthreads();
            if (tid == 0) {
                __hip_atomic_fetch_add(bar + t, 1, __ATOMIC_RELEASE, __HIP_MEMORY_SCOPE_AGENT);
                while (__hip_atomic_load(bar + t, __ATOMIC_ACQUIRE, __HIP_MEMORY_SCOPE_AGENT) < 256)
                    __builtin_amdgcn_s_sleep(2);
            }
            __syncthreads();
            __threadfence();
        }
    }
}

// ---------------- output GEMM (MFMA + permuted global_load_lds staging) ----------------
// out = H1 @ w_out + b_out. Tile 128x128, BK=32, 4 waves 2x2, wave = 64x64 = 4x4 MFMA tiles.
// Staging permutes the GLOBAL source so linear LDS writes land frag-contiguous:
// chunk c -> (rt=c>>6, quad=(c>>4)&3, l16=c&15) at LDS byte c*16. Fragment reads are then
// 64-lane contiguous ds_read_b128 -> zero bank conflicts (was 8-way on [row][32]).
__global__ __launch_bounds__(256) void out_gemm_mfma(
    const bf16* __restrict__ A, const bf16* __restrict__ Wt,
    const float* __restrict__ bias, float* __restrict__ out)
{
    __shared__ __align__(16) bf16 As[128 * 32];
    __shared__ __align__(16) bf16 Bs[128 * 32];
    int tid = threadIdx.x, w = tid >> 6, L = tid & 63, quad = L >> 4, l16 = L & 15;
    int wr = w >> 1, wc = w & 1;
    long R0 = (long)blockIdx.y * 128;
    long C0 = (long)blockIdx.x * 128;

    int c0 = tid, c1 = 256 + tid;
    const bf16* gA0 = A  + (R0 + (c0 >> 6) * 16 + (c0 & 15)) * 1024 + ((c0 >> 4) & 3) * 8;
    const bf16* gA1 = A  + (R0 + (c1 >> 6) * 16 + (c1 & 15)) * 1024 + ((c1 >> 4) & 3) * 8;
    const bf16* gB0 = Wt + (C0 + (c0 >> 6) * 16 + (c0 & 15)) * 1024 + ((c0 >> 4) & 3) * 8;
    const bf16* gB1 = Wt + (C0 + (c1 >> 6) * 16 + (c1 & 15)) * 1024 + ((c1 >> 4) & 3) * 8;
    char* sA0 = (char*)As + w * 1024;  char* sA1 = (char*)As + 4096 + w * 1024;
    char* sB0 = (char*)Bs + w * 1024;  char* sB1 = (char*)Bs + 4096 + w * 1024;

    const s8v* fA[4];
    const s8v* fB[4];
    #pragma unroll
    for (int i = 0; i < 4; i++) fA[i] = (const s8v*)As + (wr * 4 + i) * 64 + quad * 16 + l16;
    #pragma unroll
    for (int jj = 0; jj < 4; jj++) fB[jj] = (const s8v*)Bs + (wc * 4 + jj) * 64 + quad * 16 + l16;

    f4v acc[4][4] = {};

    for (int kt = 0; kt < 32; ++kt) {
        async_copy16(gA0, sA0);
        async_copy16(gA1, sA1);
        async_copy16(gB0, sB0);
        async_copy16(gB1, sB1);
        gA0 += 32; gA1 += 32; gB0 += 32; gB1 += 32;
        __syncthreads();   // vmcnt(0) drain: LDS tile ready

        s8v av[4], bv[4];
        #pragma unroll
        for (int i = 0; i < 4; i++) av[i] = *fA[i];
        #pragma unroll
        for (int jj = 0; jj < 4; jj++) bv[jj] = *fB[jj];
        #pragma unroll
        for (int i = 0; i < 4; i++)
            #pragma unroll
            for (int jj = 0; jj < 4; jj++)
                acc[i][jj] = __builtin_amdgcn_mfma_f32_16x16x32_bf16(av[i], bv[jj], acc[i][jj], 0, 0, 0);

        __syncthreads();   // reads done before next stage overwrites
    }

    #pragma unroll
    for (int i = 0; i < 4; i++) {
        #pragma unroll
        for (int jj = 0; jj < 4; jj++) {
            #pragma unroll
            for (int p = 0; p < 4; p++) {
                long row = R0 + wr * 64 + i * 16 + quad * 4 + p;
                long col = C0 + wc * 64 + jj * 16 + l16;
                if (row < 8128 && col < VV)
                    out[row * VV + col] = acc[i][jj][p] + bias[col];
            }
        }
    }
}

// ---------------- per-row log-softmax loss (single-pass online) ----------------
__global__ __launch_bounds__(256) void loss_kernel(
    const float* __restrict__ logits,
    const int* __restrict__ sent,
    float* __restrict__ rowloss)
{
    __shared__ float redm[256];
    __shared__ float reds[256];
    int r = blockIdx.x;
    int b = r / TM1, t = r % TM1;
    const float* row = logits + (long)r * VV;
    int tid = threadIdx.x;

    float mx = -INFINITY, sum = 0.0f;
    for (int v = tid; v < VV; v += 256) {
        float x = row[v];
        float M = fmaxf(mx, x);
        sum = sum * __expf(mx - M) + __expf(x - M);
        mx = M;
    }
    redm[tid] = mx; reds[tid] = sum;
    __syncthreads();
    for (int s = 128; s > 0; s >>= 1) {
        if (tid < s) {
            float m1 = redm[tid], s1 = reds[tid];
            float m2 = redm[tid + s], s2 = reds[tid + s];
            float M = fmaxf(m1, m2);
            reds[tid] = s1 * __expf(m1 - M) + s2 * __expf(m2 - M);
            redm[tid] = M;
        }
        __syncthreads();
    }
    if (tid == 0) {
        int gt = sent[b * TT + t + 1];
        float val = 0.0f;
        if (gt != 0) val = -(row[gt] - redm[0] - logf(reds[0]));
        rowloss[r] = val;
    }
}

__global__ void final_kernel(const float* __restrict__ rowloss,
                             const int* __restrict__ length,
                             float* __restrict__ out0)
{
    int b = threadIdx.x;   // 0..63
    float s = 0.0f;
    for (int t = 0; t < TM1; t++) s += rowloss[b * TM1 + t];
    s /= (float)length[b];
    #pragma unroll
    for (int off = 32; off > 0; off >>= 1) s += __shfl_down(s, off, 64);
    if (b == 0) out0[0] = s;
}

extern "C" void kernel_launch(void* const* d_in, const int* in_sizes, int n_in,
                              void* d_out, int out_size, void* d_ws, size_t ws_size,
                              hipStream_t stream) {
    const int*   sent    = (const int*)d_in[0];
    const int*   length  = (const int*)d_in[1];
    const float* wordvec = (const float*)d_in[2];
    const float* w_ih0   = (const float*)d_in[3];
    const float* w_hh0   = (const float*)d_in[4];
    const float* b0      = (const float*)d_in[5];
    const float* w_ih1   = (const float*)d_in[6];
    const float* w_hh1   = (const float*)d_in[7];
    const float* b1      = (const float*)d_in[8];
    const float* w_out   = (const float*)d_in[9];
    const float* b_out   = (const float*)d_in[10];
    float* out = (float*)d_out;

    char* W = (char*)d_ws;
    size_t o = 0;
    bf16* X      = (bf16*)(W + o); o += 128L * 64 * 320 * 2;        // 5,242,880
    bf16* wtih0  = (bf16*)(W + o); o += 4096L * 320 * 2;            // 2,621,440
    bf16* wthh0  = (bf16*)(W + o); o += 4096L * 1024 * 2;           // 8,388,608
    bf16* wtih1  = (bf16*)(W + o); o += 4096L * 1024 * 2;
    bf16* wthh1  = (bf16*)(W + o); o += 4096L * 1024 * 2;
    bf16* woutt  = (bf16*)(W + o); o += 10112L * 1024 * 2;          // 20,709,376
    bf16* H1     = (bf16*)(W + o); o += 8192L * 1024 * 2;           // 16,777,216
    // zero region (contiguous): h0b0, h0b1, h1b0, h1b1, bar
    bf16*  h0b0  = (bf16*)(W + o); o += 64L * 1024 * 2;
    bf16*  h0b1  = (bf16*)(W + o); o += 64L * 1024 * 2;
    bf16*  h1b0  = (bf16*)(W + o); o += 64L * 1024 * 2;
    bf16*  h1b1  = (bf16*)(W + o); o += 64L * 1024 * 2;
    int*   bar   = (int*)(W + o);  o += 256L * 4;
    float* rowloss = (float*)(W + o); o += 8128L * 4;

    // zero h-buffers + barrier counters: 4*131072 + 1024 = 525312 B = 131328 floats
    zero_kernel<<<513, 256, 0, stream>>>((float*)h0b0, 131328);
    // zero H1 pad rows (8128..8191) so out_gemm's A-frags never read poison/NaN
    zero_kernel<<<128, 256, 0, stream>>>((float*)(H1 + 8128L * 1024), 32768);

    embed_kernel<<<128 * 64, 64, 0, stream>>>(sent, wordvec, X);
    transpose_bf16_kernel<<<dim3(128, 10), 256, 0, stream>>>(w_ih0, wtih0, 300, 4096, 320);
    transpose_bf16_kernel<<<dim3(128, 32), 256, 0, stream>>>(w_hh0, wthh0, 1024, 4096, 1024);
    transpose_bf16_kernel<<<dim3(128, 32), 256, 0, stream>>>(w_ih1, wtih1, 1024, 4096, 1024);
    transpose_bf16_kernel<<<dim3(128, 32), 256, 0, stream>>>(w_hh1, wthh1, 1024, 4096, 1024);
    transpose_bf16_kernel<<<dim3(316, 32), 256, 0, stream>>>(w_out, woutt, 1024, VV, 1024);

    // whole recurrence in one persistent kernel (128 ticks, 127 grid barriers)
    lstm_persistent<<<256, 512, 0, stream>>>(
        X, wtih0, wthh0, wtih1, wthh1, b0, b1,
        h0b0, h0b1, h1b0, h1b1, H1, bar);

    out_gemm_mfma<<<dim3(79, 64), 256, 0, stream>>>(H1, woutt, b_out, out + 1);
    loss_kernel<<<TM1 * BB, 256, 0, stream>>>(out + 1, sent, rowloss);
    final_kernel<<<1, 64, 0, stream>>>(rowloss, length, out);
}